// Round 1
// baseline (162.341 us; speedup 1.0000x reference)
//
#include <hip/hip_runtime.h>

#define TPB    256
#define XPT    4                 // x points per thread (register blocking)
#define XTILE  (TPB * XPT)       // 1024 x points per block
#define YCHUNK 512               // y points per block (grid.y chunks)
#define YTILE  256               // y points staged in LDS at a time
#define NPTS   8192
#define NB     4
#define TOTPTS (NB * NPTS)       // 32768

// ---------------------------------------------------------------------------
// ws layout (as unsigned):
//   [0,       32768)  mins_true  bits (min squared dist, fp32 bit pattern)
//   [32768,   65536)  mins_pred  bits
//   [65536,   65538)  sums[2] as float (sum_true, sum_pred)
// ---------------------------------------------------------------------------

__global__ void __launch_bounds__(TPB) init_ws(unsigned* __restrict__ ws) {
    int i = blockIdx.x * TPB + threadIdx.x;
    if (i < 2 * TOTPTS)          ws[i] = 0x7F800000u;  // +inf bits
    else if (i < 2 * TOTPTS + 2) ws[i] = 0u;           // sums = 0.0f
}

// For each x point: min over a YCHUNK-range of y points of squared distance.
// grid: (NPTS/XTILE, NPTS/YCHUNK, NB)
__global__ void __launch_bounds__(TPB) nnmin_kernel(
        const float* __restrict__ X, const float* __restrict__ Y,
        unsigned* __restrict__ outbits)
{
    __shared__ float4 sY4[(YTILE * 3) / 4];   // 3 KB
    float* sY = (float*)sY4;

    const int b     = blockIdx.z;
    const int x0    = blockIdx.x * XTILE;
    const int ybase = blockIdx.y * YCHUNK;
    const float* Xb = X + (size_t)b * NPTS * 3;
    const float* Yb = Y + (size_t)b * NPTS * 3;
    const int t = threadIdx.x;

    float xx[XPT], xy[XPT], xz[XPT], m2[XPT];
#pragma unroll
    for (int i = 0; i < XPT; ++i) {
        int xi = x0 + i * TPB + t;
        xx[i] = Xb[xi * 3 + 0];
        xy[i] = Xb[xi * 3 + 1];
        xz[i] = Xb[xi * 3 + 2];
        m2[i] = 3.0e38f;
    }

    for (int yt = 0; yt < YCHUNK; yt += YTILE) {
        __syncthreads();
        // stage YTILE y-points (768 floats) coalesced: 3 per thread
#pragma unroll
        for (int i = 0; i < 3; ++i)
            sY[i * TPB + t] = Yb[(size_t)(ybase + yt) * 3 + i * TPB + t];
        __syncthreads();

#pragma unroll 2
        for (int j = 0; j < YTILE; j += 4) {
            const int o = (j >> 2) * 3;
            // 4 y-points = 12 floats = 3 float4 broadcast reads
            float4 A = sY4[o], B4 = sY4[o + 1], C4 = sY4[o + 2];
            float ys[4][3] = {{A.x,  A.y,  A.z},
                              {A.w,  B4.x, B4.y},
                              {B4.z, B4.w, C4.x},
                              {C4.y, C4.z, C4.w}};
#pragma unroll
            for (int p = 0; p < 4; ++p) {
#pragma unroll
                for (int i = 0; i < XPT; ++i) {
                    float dx = xx[i] - ys[p][0];
                    float dy = xy[i] - ys[p][1];
                    float dz = xz[i] - ys[p][2];
                    float d2 = dx * dx + dy * dy + dz * dz;
                    m2[i] = fminf(m2[i], d2);
                }
            }
        }
    }

    // combine across y-chunks: atomicMin on fp32 bit pattern (d2 >= 0)
#pragma unroll
    for (int i = 0; i < XPT; ++i) {
        int xi = x0 + i * TPB + t;
        atomicMin(&outbits[b * NPTS + xi], __float_as_uint(m2[i]));
    }
}

// sqrt the squared-dist mins, write mins_seeds to out[1..], reduce both sums.
__global__ void __launch_bounds__(TPB) finalize_kernel(
        const unsigned* __restrict__ ws, float* __restrict__ out,
        float* __restrict__ sums)
{
    int i = blockIdx.x * TPB + threadIdx.x;     // 0 .. 2*TOTPTS-1
    int isPred = (i >= TOTPTS) ? 1 : 0;         // uniform per block
    float d = sqrtf(__uint_as_float(ws[i]));
    if (isPred) out[1 + (i - TOTPTS)] = d;      // mins_seeds

    // wave-64 shuffle reduction, then one atomicAdd per wave
#pragma unroll
    for (int off = 32; off > 0; off >>= 1)
        d += __shfl_down(d, off, 64);
    if ((threadIdx.x & 63) == 0) atomicAdd(&sums[isPred], d);
}

__global__ void scalar_kernel(const float* __restrict__ sums,
                              float* __restrict__ out) {
    if (threadIdx.x == 0 && blockIdx.x == 0)
        out[0] = (sums[0] + sums[1]) * (1.0f / (float)TOTPTS);
}

extern "C" void kernel_launch(void* const* d_in, const int* in_sizes, int n_in,
                              void* d_out, int out_size, void* d_ws, size_t ws_size,
                              hipStream_t stream) {
    const float* truep = (const float*)d_in[0];   // [4, 8192, 3] fp32
    const float* predp = (const float*)d_in[1];   // [4, 8192, 3] fp32
    float* out = (float*)d_out;                   // [1 + 32768] fp32
    unsigned* ws = (unsigned*)d_ws;
    unsigned* minsTrue = ws;                      // B*N
    unsigned* minsPred = ws + TOTPTS;             // B*M
    float* sums = (float*)(ws + 2 * TOTPTS);      // 2 floats

    init_ws<<<(2 * TOTPTS + 2 + TPB - 1) / TPB, TPB, 0, stream>>>(ws);

    dim3 grid(NPTS / XTILE, NPTS / YCHUNK, NB);   // (8, 16, 4) = 512 blocks
    // direction A: for each true point, nearest pred -> mins  [B,N]
    nnmin_kernel<<<grid, TPB, 0, stream>>>(truep, predp, minsTrue);
    // direction B: for each pred point, nearest true -> mins_seeds [B,M]
    nnmin_kernel<<<grid, TPB, 0, stream>>>(predp, truep, minsPred);

    finalize_kernel<<<(2 * TOTPTS) / TPB, TPB, 0, stream>>>(ws, out, sums);
    scalar_kernel<<<1, 64, 0, stream>>>(sums, out);
}

// Round 2
// 125.568 us; speedup vs baseline: 1.2928x; 1.2928x over previous
//
#include <hip/hip_runtime.h>

#define TPB    256
#define XPT    8                 // x points per thread (register blocking)
#define XTILE  (TPB * XPT)       // 2048 x points per block
#define GY     32                // y chunks
#define YTILE  256               // = NPTS / GY, one LDS stage per block
#define NPTS   8192
#define NB     4
#define TOTPTS (NB * NPTS)       // 32768

// ---------------------------------------------------------------------------
// ws layout (as unsigned):
//   [0,       32768)  dir A: per-true-point min of t = d^2/2 (fp32 bits, >=0)
//   [32768,   65536)  dir B: per-pred-point min (mins_seeds)
//   [65536,   65538)  sums[2] as float (sum_true, sum_pred)
// init: memset 0x7F -> 0x7F7F7F7F = 3.39e38f, larger than any t, and a valid
// unsigned upper bound for the bit-pattern atomicMin (all stored values >= 0).
// ---------------------------------------------------------------------------

// Both directions in one launch. blockIdx.z: [0,4) dir A (X=true, Y=pred),
// [4,8) dir B (X=pred, Y=true). grid = (NPTS/XTILE, GY, 2*NB) = (4, 32, 8).
__global__ void __launch_bounds__(TPB) nnmin_both(
        const float* __restrict__ T, const float* __restrict__ P,
        unsigned* __restrict__ ws)
{
    __shared__ float4 sY[YTILE];   // (yx, yy, yz, 0.5*|y|^2) per point, 4 KB

    const int z   = blockIdx.z;
    const int dir = z >> 2;
    const int b   = z & 3;
    const float* Xb = (dir ? P : T) + (size_t)b * NPTS * 3;
    const float* Yb = (dir ? T : P) + (size_t)b * NPTS * 3;
    unsigned* outb = ws + dir * TOTPTS + b * NPTS;

    const int t  = threadIdx.x;
    const int x0 = blockIdx.x * XTILE;
    const int y0 = blockIdx.y * YTILE;

    // stage Y tile (256 points) with precomputed hy = 0.5*|y|^2
    {
        const float* yp = Yb + (size_t)(y0 + t) * 3;
        float yx = yp[0], yy = yp[1], yz = yp[2];
        sY[t] = make_float4(yx, yy, yz, 0.5f * (yx * yx + yy * yy + yz * yz));
    }

    // x points in registers; overlap these global loads with others' staging
    float xx[XPT], xy[XPT], xz[XPT], hx[XPT], m[XPT];
#pragma unroll
    for (int i = 0; i < XPT; ++i) {
        const float* xp = Xb + (size_t)(x0 + i * TPB + t) * 3;
        xx[i] = xp[0]; xy[i] = xp[1]; xz[i] = xp[2];
        hx[i] = 0.5f * (xx[i] * xx[i] + xy[i] * xy[i] + xz[i] * xz[i]);
        m[i]  = 3.0e38f;
    }
    __syncthreads();

    // min_t over tile: t = hx + hy - x.y   (= d^2/2, monotone in d)
    // 5 VALU ops per pair, 1 broadcast ds_read_b128 per 8 pairs
#pragma unroll 4
    for (int j = 0; j < YTILE; ++j) {
        float4 y = sY[j];
#pragma unroll
        for (int i = 0; i < XPT; ++i) {
            float acc = hx[i] + y.w;
            acc = fmaf(-xx[i], y.x, acc);
            acc = fmaf(-xy[i], y.y, acc);
            acc = fmaf(-xz[i], y.z, acc);
            m[i] = fminf(m[i], acc);
        }
    }

    // clamp at 0 (commutes with cross-chunk min), combine via u32 atomicMin
#pragma unroll
    for (int i = 0; i < XPT; ++i) {
        unsigned u = __float_as_uint(fmaxf(m[i], 0.0f));
        atomicMin(&outb[x0 + i * TPB + t], u);
    }
}

// d = sqrt(2*t); write mins_seeds to out[1..]; reduce both sums.
__global__ void __launch_bounds__(TPB) finalize_kernel(
        const unsigned* __restrict__ ws, float* __restrict__ out,
        float* __restrict__ sums)
{
    int i = blockIdx.x * TPB + threadIdx.x;     // 0 .. 2*TOTPTS-1
    int isPred = (i >= TOTPTS) ? 1 : 0;         // uniform per block
    float tmin = __uint_as_float(ws[i]);
    float d = sqrtf(tmin + tmin);
    if (isPred) out[1 + (i - TOTPTS)] = d;      // mins_seeds

#pragma unroll
    for (int off = 32; off > 0; off >>= 1)
        d += __shfl_down(d, off, 64);
    if ((threadIdx.x & 63) == 0) atomicAdd(&sums[isPred], d);
}

__global__ void scalar_kernel(const float* __restrict__ sums,
                              float* __restrict__ out) {
    if (threadIdx.x == 0 && blockIdx.x == 0)
        out[0] = (sums[0] + sums[1]) * (1.0f / (float)TOTPTS);
}

extern "C" void kernel_launch(void* const* d_in, const int* in_sizes, int n_in,
                              void* d_out, int out_size, void* d_ws, size_t ws_size,
                              hipStream_t stream) {
    const float* truep = (const float*)d_in[0];   // [4, 8192, 3] fp32
    const float* predp = (const float*)d_in[1];   // [4, 8192, 3] fp32
    float* out = (float*)d_out;                   // [1 + 32768] fp32
    unsigned* ws = (unsigned*)d_ws;
    float* sums = (float*)(ws + 2 * TOTPTS);      // 2 floats

    // 0x7F7F7F7F = 3.39e38f: > any t, valid unsigned floor for atomicMin
    hipMemsetAsync(ws, 0x7F, (size_t)2 * TOTPTS * 4, stream);
    hipMemsetAsync(sums, 0, 2 * sizeof(float), stream);

    dim3 grid(NPTS / XTILE, GY, 2 * NB);          // (4, 32, 8) = 1024 blocks
    nnmin_both<<<grid, TPB, 0, stream>>>(truep, predp, ws);

    finalize_kernel<<<(2 * TOTPTS) / TPB, TPB, 0, stream>>>(ws, out, sums);
    scalar_kernel<<<1, 64, 0, stream>>>(sums, out);
}

// Round 3
// 103.056 us; speedup vs baseline: 1.5753x; 1.2184x over previous
//
#include <hip/hip_runtime.h>

#define TPB    256
#define XPT    8                 // x points per thread (register blocking)
#define XTILE  (TPB * XPT)       // 2048 x points per block
#define GY     32                // y chunks
#define YTILE  256               // = NPTS / GY, one LDS stage per block
#define NPTS   8192
#define NB     4
#define TOTPTS (NB * NPTS)       // 32768
#define NSLICE (2 * NB)          // 8 (dir, batch) slices per chunk
#define WS2_FLOATS ((size_t)GY * NSLICE * NPTS)   // 2,097,152 floats = 8 MB
#define NPARTIAL ((2 * TOTPTS) / 64)              // 1024 per-wave partials

// ---------------------------------------------------------------------------
// Chunked path ws layout (floats):
//   [0, WS2_FLOATS)           per-chunk partial mins of t' = hy - x.y
//                             slice = chunk*NSLICE + (dir*4 + b), contiguous x
//   [WS2_FLOATS, +NPARTIAL)   per-wave partial sums from finalize
// No initialization required: every word is written before it is read.
// Fallback (small ws) uses flip-key u32 atomicMin + 0xFF memset init.
// ---------------------------------------------------------------------------

// blockIdx.z: dir*4 + b.  grid = (NPTS/XTILE, GY, 2*NB) = (4, 32, 8).
// Inner loop: 4 VALU ops per pair (3 fma + min); hx hoisted to finalize.
__global__ void __launch_bounds__(TPB) nnmin_chunk(
        const float* __restrict__ T, const float* __restrict__ P,
        float* __restrict__ ws2)
{
    __shared__ float4 sY[YTILE];   // (yx, yy, yz, 0.5*|y|^2), 4 KB

    const int z   = blockIdx.z;
    const int dir = z >> 2;
    const int b   = z & 3;
    const float* Xb = (dir ? P : T) + (size_t)b * NPTS * 3;
    const float* Yb = (dir ? T : P) + (size_t)b * NPTS * 3;

    const int t  = threadIdx.x;
    const int x0 = blockIdx.x * XTILE;
    const int y0 = blockIdx.y * YTILE;

    {   // stage Y tile with precomputed hy = 0.5*|y|^2
        const float* yp = Yb + (size_t)(y0 + t) * 3;
        float yx = yp[0], yy = yp[1], yz = yp[2];
        sY[t] = make_float4(yx, yy, yz, 0.5f * (yx * yx + yy * yy + yz * yz));
    }

    float xx[XPT], xy[XPT], xz[XPT], m[XPT];
#pragma unroll
    for (int i = 0; i < XPT; ++i) {
        const float* xp = Xb + (size_t)(x0 + i * TPB + t) * 3;
        xx[i] = xp[0]; xy[i] = xp[1]; xz[i] = xp[2];
        m[i]  = 3.0e38f;
    }
    __syncthreads();

    // t' = hy - x.y  (add hx later; monotone in d for fixed x)
#pragma unroll 4
    for (int j = 0; j < YTILE; ++j) {
        float4 y = sY[j];
#pragma unroll
        for (int i = 0; i < XPT; ++i) {
            float acc = fmaf(-xx[i], y.x, y.w);
            acc = fmaf(-xy[i], y.y, acc);
            acc = fmaf(-xz[i], y.z, acc);
            m[i] = fminf(m[i], acc);
        }
    }

    // disjoint slice per (chunk, dir, b): plain coalesced stores, no atomics
    float* o = ws2 + ((size_t)blockIdx.y * NSLICE + z) * NPTS + x0 + t;
#pragma unroll
    for (int i = 0; i < XPT; ++i) o[i * TPB] = m[i];
}

// Fallback: combine across chunks via atomicMin on order-preserving u32 key.
__global__ void __launch_bounds__(TPB) nnmin_atomic(
        const float* __restrict__ T, const float* __restrict__ P,
        unsigned* __restrict__ keys)
{
    __shared__ float4 sY[YTILE];
    const int z   = blockIdx.z;
    const int dir = z >> 2;
    const int b   = z & 3;
    const float* Xb = (dir ? P : T) + (size_t)b * NPTS * 3;
    const float* Yb = (dir ? T : P) + (size_t)b * NPTS * 3;
    const int t  = threadIdx.x;
    const int x0 = blockIdx.x * XTILE;
    const int y0 = blockIdx.y * YTILE;
    {
        const float* yp = Yb + (size_t)(y0 + t) * 3;
        float yx = yp[0], yy = yp[1], yz = yp[2];
        sY[t] = make_float4(yx, yy, yz, 0.5f * (yx * yx + yy * yy + yz * yz));
    }
    float xx[XPT], xy[XPT], xz[XPT], m[XPT];
#pragma unroll
    for (int i = 0; i < XPT; ++i) {
        const float* xp = Xb + (size_t)(x0 + i * TPB + t) * 3;
        xx[i] = xp[0]; xy[i] = xp[1]; xz[i] = xp[2];
        m[i]  = 3.0e38f;
    }
    __syncthreads();
#pragma unroll 4
    for (int j = 0; j < YTILE; ++j) {
        float4 y = sY[j];
#pragma unroll
        for (int i = 0; i < XPT; ++i) {
            float acc = fmaf(-xx[i], y.x, y.w);
            acc = fmaf(-xy[i], y.y, acc);
            acc = fmaf(-xz[i], y.z, acc);
            m[i] = fminf(m[i], acc);
        }
    }
    unsigned* o = keys + (size_t)dir * TOTPTS + (size_t)b * NPTS + x0 + t;
#pragma unroll
    for (int i = 0; i < XPT; ++i) {
        unsigned bb = __float_as_uint(m[i]);
        unsigned k  = bb ^ ((bb & 0x80000000u) ? 0xFFFFFFFFu : 0x80000000u);
        atomicMin(&o[i * TPB], k);
    }
}

// Reduce chunks (or decode key), add hx, sqrt; write mins_seeds; per-wave sums.
__global__ void __launch_bounds__(TPB) finalize_kernel(
        const float* __restrict__ ws2, const unsigned* __restrict__ keys,
        int chunked,
        const float* __restrict__ T, const float* __restrict__ P,
        float* __restrict__ out, float* __restrict__ partials)
{
    int i   = blockIdx.x * TPB + threadIdx.x;   // 0 .. 2*TOTPTS-1
    int dir = (i >= TOTPTS) ? 1 : 0;            // uniform per block
    int idx = i - dir * TOTPTS;
    int b   = idx >> 13;                        // / NPTS
    int x   = idx & (NPTS - 1);

    float m;
    if (chunked) {
        m = 3.0e38f;
        const float* p = ws2 + ((size_t)dir * NB + b) * NPTS + x;
#pragma unroll
        for (int c = 0; c < GY; ++c)
            m = fminf(m, p[(size_t)c * NSLICE * NPTS]);
    } else {
        unsigned k  = keys[i];
        unsigned bb = (k & 0x80000000u) ? (k ^ 0x80000000u) : ~k;
        m = __uint_as_float(bb);
    }

    const float* xp = (dir ? P : T) + ((size_t)b * NPTS + x) * 3;
    float a0 = xp[0], a1 = xp[1], a2 = xp[2];
    float hx = 0.5f * (a0 * a0 + a1 * a1 + a2 * a2);
    float d  = sqrtf(fmaxf(2.0f * (hx + m), 0.0f));
    if (dir) out[1 + idx] = d;                  // mins_seeds

#pragma unroll
    for (int off = 32; off > 0; off >>= 1)
        d += __shfl_down(d, off, 64);
    if ((threadIdx.x & 63) == 0) partials[i >> 6] = d;  // plain store, no init
}

// Single-wave final reduction of 1024 per-wave partials.
__global__ void scalar_kernel(const float* __restrict__ partials,
                              float* __restrict__ out) {
    int t = threadIdx.x;                        // 64 threads
    float s = 0.0f;
#pragma unroll
    for (int k = 0; k < NPARTIAL / 64; ++k)     // 16 partials per lane
        s += partials[t * (NPARTIAL / 64) + k];
#pragma unroll
    for (int off = 32; off > 0; off >>= 1)
        s += __shfl_down(s, off, 64);
    if (t == 0) out[0] = s * (1.0f / (float)TOTPTS);
}

extern "C" void kernel_launch(void* const* d_in, const int* in_sizes, int n_in,
                              void* d_out, int out_size, void* d_ws, size_t ws_size,
                              hipStream_t stream) {
    const float* truep = (const float*)d_in[0];   // [4, 8192, 3] fp32
    const float* predp = (const float*)d_in[1];   // [4, 8192, 3] fp32
    float* out = (float*)d_out;                   // [1 + 32768] fp32

    dim3 grid(NPTS / XTILE, GY, 2 * NB);          // (4, 32, 8) = 1024 blocks

    const size_t need = WS2_FLOATS * 4 + NPARTIAL * 4;
    int chunked = (ws_size >= need) ? 1 : 0;
    float*    ws2  = (float*)d_ws;
    unsigned* keys = (unsigned*)d_ws;
    float* partials;

    if (chunked) {
        partials = (float*)d_ws + WS2_FLOATS;
        nnmin_chunk<<<grid, TPB, 0, stream>>>(truep, predp, ws2);
    } else {
        partials = (float*)((unsigned*)d_ws + 2 * TOTPTS);
        // 0xFFFFFFFF = max key: valid floor for flip-key atomicMin
        hipMemsetAsync(d_ws, 0xFF, (size_t)2 * TOTPTS * 4, stream);
        nnmin_atomic<<<grid, TPB, 0, stream>>>(truep, predp, keys);
    }

    finalize_kernel<<<(2 * TOTPTS) / TPB, TPB, 0, stream>>>(
        ws2, keys, chunked, truep, predp, out, partials);
    scalar_kernel<<<1, 64, 0, stream>>>(partials, out);
}